// Round 1
// baseline (395.788 us; speedup 1.0000x reference)
//
#include <hip/hip_runtime.h>
#include <hip/hip_bf16.h>

typedef __bf16 bf16x8 __attribute__((ext_vector_type(8)));
typedef float  f32x4  __attribute__((ext_vector_type(4)));

// ---- workspace layout (bytes) ----
#define WS_B1T   0         // [512][128] bf16: [Wqkv | Wqg]^T  (n-major)
#define WS_B2T   131072    // [256][128] bf16: [Wout | 0.1*Woutg]^T
#define WS_BIAS1 196608    // f32[512] = [bqkv | bqg]
#define WS_BIAS2 198656    // f32[128] = bout + 0.1*boutg
#define WS_KVG   199168    // f32[2][8h][8g][16d] global K,V

__device__ __forceinline__ unsigned short f2bf(float x) {
    unsigned int u = __float_as_uint(x);
    unsigned int r = (u + 0x7fffu + ((u >> 16) & 1u)) >> 16;
    return (unsigned short)r;
}

// ---------------- prep: weights -> bf16 transposed, global KV, biases ----------------
__global__ __launch_bounds__(256) void wattn_prep(
    const float* __restrict__ Wqkv, const float* __restrict__ bqkv,
    const float* __restrict__ Wout, const float* __restrict__ bout,
    const float* __restrict__ Wqg,  const float* __restrict__ bqg,
    const float* __restrict__ Wkvg, const float* __restrict__ bkvg,
    const float* __restrict__ Woutg,const float* __restrict__ boutg,
    const float* __restrict__ gtok, unsigned char* __restrict__ ws)
{
    const int blk = blockIdx.x, tid = threadIdx.x;
    unsigned short* B1t = (unsigned short*)(ws + WS_B1T);
    unsigned short* B2t = (unsigned short*)(ws + WS_B2T);
    float* bias1 = (float*)(ws + WS_BIAS1);
    float* bias2 = (float*)(ws + WS_BIAS2);
    float* kvg   = (float*)(ws + WS_KVG);

    if (blk == 0) {
        // global tokens KV: kv[g][j] = sum_c gtok[g][c]*Wkvg[c][j] + bkvg[j], j in [0,256)
        for (int i = tid; i < 2048; i += 256) {
            const int g = i >> 8, j = i & 255;
            float acc = bkvg[j];
            for (int c = 0; c < 128; ++c) acc += gtok[g*128 + c] * Wkvg[c*256 + j];
            const int half = j >> 7, hh = (j >> 4) & 7, d = j & 15;
            kvg[half*1024 + hh*128 + g*16 + d] = acc;
        }
        for (int i = tid; i < 512; i += 256) bias1[i] = (i < 384) ? bqkv[i] : bqg[i - 384];
        for (int i = tid; i < 128; i += 256) bias2[i] = bout[i] + 0.1f * boutg[i];
    } else if (blk <= 8) {
        const int n0 = (blk - 1) * 64;
        for (int i = tid; i < 64 * 128; i += 256) {
            const int n = n0 + (i >> 7), k = i & 127;
            const float w = (n < 384) ? Wqkv[k*384 + n] : Wqg[k*128 + (n - 384)];
            B1t[n*128 + k] = f2bf(w);
        }
    } else {  // blk 9..12
        const int n0 = (blk - 9) * 64;
        for (int i = tid; i < 64 * 128; i += 256) {
            const int n = n0 + (i >> 7), k = i & 127;
            const float w = (n < 128) ? Wout[k*128 + n] : 0.1f * Woutg[k*128 + (n - 128)];
            B2t[n*128 + k] = f2bf(w);
        }
    }
}

// ---------------- fused per-window kernel ----------------
// LDS map (64 KiB):
//   [0,16K)   Xb  features (token-major, swz)   -> phase C+: low half of P chunks
//   [16K,32K) Qb  q (token-major, swz)          -> phase C+: high half of P chunks
//   [32K,48K) Kb  k (token-major, swz)          -> phase C-PV+: Ob attn-out
//   [48K,64K) Vt  v transposed [dim][tok] (swz) -> phase D+: Gb global-out (token-major)
__global__ __launch_bounds__(512, 2) void wattn_main(
    const float* __restrict__ feat,
    const unsigned char* __restrict__ ws,
    float* __restrict__ out)
{
    __shared__ __align__(16) unsigned char lds[65536];
    const int tid  = threadIdx.x;
    const int wave = tid >> 6;
    const int lane = tid & 63;
    const int rg   = lane >> 4;   // row-group / k-chunk selector
    const int cl   = lane & 15;   // col-in-tile

    const int blk = blockIdx.x;
    const int b   = blk >> 9;
    const int rem = blk & 511;
    const int base_row = b*32768 + (rem >> 6)*4096 + ((rem >> 3) & 7)*128 + (rem & 7)*4;

    const uint4 z4i = {0u, 0u, 0u, 0u};
    const bf16x8 zfrag = __builtin_bit_cast(bf16x8, z4i);

    // ---------- Phase A: stage window features as bf16 (swizzled) ----------
    {
        const int row = tid >> 3, j = tid & 7;
        const int grow = base_row + (row >> 4)*1024 + ((row >> 2) & 3)*32 + (row & 3);
        const float* src = feat + grow*128;
        #pragma unroll
        for (int hh = 0; hh < 2; ++hh) {
            const int col = hh*64 + j*8;
            float4 a = *(const float4*)(src + col);
            float4 c = *(const float4*)(src + col + 4);
            uint4 p;
            p.x = (unsigned)f2bf(a.x) | ((unsigned)f2bf(a.y) << 16);
            p.y = (unsigned)f2bf(a.z) | ((unsigned)f2bf(a.w) << 16);
            p.z = (unsigned)f2bf(c.x) | ((unsigned)f2bf(c.y) << 16);
            p.w = (unsigned)f2bf(c.z) | ((unsigned)f2bf(c.w) << 16);
            *(uint4*)(lds + ((row*256 + col*2) ^ ((row & 7) << 4))) = p;
        }
    }
    __syncthreads();  // barrier 1

    // ---------- Phase B: [q k v | qg] = X @ [Wqkv | Wqg] + bias ----------
    // wave owns n-tiles {3w, 3w+1, 3w+2, 24+w}; n-tile 24+w == head w of qg
    f32x4 acc[4][4];
    {
        const unsigned short* B1t = (const unsigned short*)(ws + WS_B1T);
        const float* bias1 = (const float*)(ws + WS_BIAS1);
        int ntile[4] = {3*wave, 3*wave + 1, 3*wave + 2, 24 + wave};
        #pragma unroll
        for (int i = 0; i < 4; ++i) {
            const float bv = bias1[ntile[i]*16 + cl];
            f32x4 t = {bv, bv, bv, bv};
            #pragma unroll
            for (int mt = 0; mt < 4; ++mt) acc[mt][i] = t;
        }
        #pragma unroll
        for (int ks = 0; ks < 4; ++ks) {
            bf16x8 afr[4];
            #pragma unroll
            for (int mt = 0; mt < 4; ++mt) {
                const int row = mt*16 + cl, col = ks*32 + rg*8;
                afr[mt] = *(const bf16x8*)(lds + ((row*256 + col*2) ^ ((row & 7) << 4)));
            }
            #pragma unroll
            for (int i = 0; i < 4; ++i) {
                bf16x8 bfr = *(const bf16x8*)(B1t + ntile[i]*16*128 + cl*128 + ks*32 + rg*8);
                #pragma unroll
                for (int mt = 0; mt < 4; ++mt)
                    acc[mt][i] = __builtin_amdgcn_mfma_f32_16x16x32_bf16(afr[mt], bfr, acc[mt][i], 0, 0, 0);
            }
        }
    }
    // keep this wave's head-qg in registers
    f32x4 qg[4];
    #pragma unroll
    for (int mt = 0; mt < 4; ++mt) qg[mt] = acc[mt][3];

    // scatter q,k (token-major) and v (transposed [dim][tok]) to LDS as bf16
    #pragma unroll
    for (int i = 0; i < 3; ++i) {
        const int nt = 3*wave + i;
        const int n  = nt*16 + cl;
        if (nt < 8) {            // Q  -> [16K,32K)
            #pragma unroll
            for (int mt = 0; mt < 4; ++mt)
                #pragma unroll
                for (int r = 0; r < 4; ++r) {
                    const int row = mt*16 + rg*4 + r;
                    *(unsigned short*)(lds + 16384 + ((row*256 + n*2) ^ ((row & 7) << 4))) = f2bf(acc[mt][i][r]);
                }
        } else if (nt < 16) {    // K  -> [32K,48K)
            const int c = n - 128;
            #pragma unroll
            for (int mt = 0; mt < 4; ++mt)
                #pragma unroll
                for (int r = 0; r < 4; ++r) {
                    const int row = mt*16 + rg*4 + r;
                    *(unsigned short*)(lds + 32768 + ((row*256 + c*2) ^ ((row & 7) << 4))) = f2bf(acc[mt][i][r]);
                }
        } else {                 // V^T -> [48K,64K)
            const int dv = n - 256;
            #pragma unroll
            for (int mt = 0; mt < 4; ++mt)
                #pragma unroll
                for (int r = 0; r < 4; ++r) {
                    const int tok = mt*16 + rg*4 + r;
                    *(unsigned short*)(lds + 49152 + ((dv*128 + tok*2) ^ ((dv & 7) << 4))) = f2bf(acc[mt][i][r]);
                }
        }
    }
    __syncthreads();  // barrier 2

    // ---------- Phase C: local attention, one head per wave ----------
    const int h = wave;
    f32x4 s[4][4];
    {
        bf16x8 qf[4], kf[4];
        #pragma unroll
        for (int mt = 0; mt < 4; ++mt) {
            if (rg < 2) {
                const int row = mt*16 + cl, col = h*16 + rg*8;
                qf[mt] = *(const bf16x8*)(lds + 16384 + ((row*256 + col*2) ^ ((row & 7) << 4)));
            } else qf[mt] = zfrag;   // zero-pad k=16..31
        }
        #pragma unroll
        for (int kt = 0; kt < 4; ++kt) {
            if (rg < 2) {
                const int row = kt*16 + cl, col = h*16 + rg*8;
                kf[kt] = *(const bf16x8*)(lds + 32768 + ((row*256 + col*2) ^ ((row & 7) << 4)));
            } else kf[kt] = zfrag;
        }
        const f32x4 z4 = {0.f, 0.f, 0.f, 0.f};
        #pragma unroll
        for (int mt = 0; mt < 4; ++mt)
            #pragma unroll
            for (int kt = 0; kt < 4; ++kt)
                s[mt][kt] = __builtin_amdgcn_mfma_f32_16x16x32_bf16(qf[mt], kf[kt], z4, 0, 0, 0);
    }
    // wave-parallel softmax over 64 keys (rows live across 16-lane groups + 4 kt accs)
    float rinv[4][4];
    #pragma unroll
    for (int mt = 0; mt < 4; ++mt)
        #pragma unroll
        for (int r = 0; r < 4; ++r) {
            float m = fmaxf(fmaxf(s[mt][0][r], s[mt][1][r]), fmaxf(s[mt][2][r], s[mt][3][r]));
            m = fmaxf(m, __shfl_xor(m, 1));
            m = fmaxf(m, __shfl_xor(m, 2));
            m = fmaxf(m, __shfl_xor(m, 4));
            m = fmaxf(m, __shfl_xor(m, 8));
            float sm = 0.f;
            #pragma unroll
            for (int kt = 0; kt < 4; ++kt) {
                const float e = __expf((s[mt][kt][r] - m) * 0.25f);
                s[mt][kt][r] = e;
                sm += e;
            }
            sm += __shfl_xor(sm, 1);
            sm += __shfl_xor(sm, 2);
            sm += __shfl_xor(sm, 4);
            sm += __shfl_xor(sm, 8);
            rinv[mt][r] = 1.0f / sm;
        }
    __syncthreads();  // barrier 3: Xb/Qb/Kb reusable

    // P chunk round-trip (C-layout -> A-layout) + PV, 32 keys at a time
    f32x4 o[4];
    {
        const f32x4 z4 = {0.f, 0.f, 0.f, 0.f};
        #pragma unroll
        for (int mt = 0; mt < 4; ++mt) o[mt] = z4;
    }
    unsigned char* Pw = lds + wave*4096;   // per-wave [64][32] bf16, chunk-swizzled
    #pragma unroll
    for (int ks = 0; ks < 2; ++ks) {
        #pragma unroll
        for (int kk = 0; kk < 2; ++kk) {
            const int kt = ks*2 + kk;
            #pragma unroll
            for (int mt = 0; mt < 4; ++mt)
                #pragma unroll
                for (int r = 0; r < 4; ++r) {
                    const int row = mt*16 + rg*4 + r;
                    const int c   = kk*16 + cl;
                    const float p = s[mt][kt][r] * rinv[mt][r];
                    const int off = row*64 + ((((c >> 3) ^ ((row >> 1) & 3))) << 4) + (c & 7)*2;
                    *(unsigned short*)(Pw + off) = f2bf(p);
                }
        }
        const int vrow = h*16 + cl;  // dim
        const bf16x8 vb = *(const bf16x8*)(lds + 49152 + ((vrow*128 + (ks*32 + rg*8)*2) ^ ((vrow & 7) << 4)));
        #pragma unroll
        for (int mt = 0; mt < 4; ++mt) {
            const int prow = mt*16 + cl;
            const bf16x8 pa = *(const bf16x8*)(Pw + prow*64 + (((rg ^ ((prow >> 1) & 3))) << 4));
            o[mt] = __builtin_amdgcn_mfma_f32_16x16x32_bf16(pa, vb, o[mt], 0, 0, 0);
        }
    }
    // attn-out -> Ob (Kb region), token-major bf16
    #pragma unroll
    for (int mt = 0; mt < 4; ++mt)
        #pragma unroll
        for (int r = 0; r < 4; ++r) {
            const int row = mt*16 + rg*4 + r;
            const int col = h*16 + cl;
            *(unsigned short*)(lds + 32768 + ((row*256 + col*2) ^ ((row & 7) << 4))) = f2bf(o[mt][r]);
        }
    __syncthreads();  // barrier 4: Vt free

    // ---------- Phase D: global-token cross attention (VALU), head per wave ----------
    {
        const float* kvg = (const float*)(ws + WS_KVG);
        float kgr[8], vgr[8];
        #pragma unroll
        for (int g = 0; g < 8; ++g) {
            kgr[g] = kvg[h*128 + g*16 + cl];
            vgr[g] = kvg[1024 + h*128 + g*16 + cl];
        }
        #pragma unroll
        for (int mt = 0; mt < 4; ++mt)
            #pragma unroll
            for (int r = 0; r < 4; ++r) {
                const float qv = qg[mt][r];
                float lg[8];
                #pragma unroll
                for (int g = 0; g < 8; ++g) {
                    float p = qv * kgr[g];
                    p += __shfl_xor(p, 1);
                    p += __shfl_xor(p, 2);
                    p += __shfl_xor(p, 4);
                    p += __shfl_xor(p, 8);
                    lg[g] = p;
                }
                float m = fmaxf(fmaxf(fmaxf(lg[0], lg[1]), fmaxf(lg[2], lg[3])),
                                fmaxf(fmaxf(lg[4], lg[5]), fmaxf(lg[6], lg[7])));
                float sm = 0.f, go = 0.f;
                #pragma unroll
                for (int g = 0; g < 8; ++g) {
                    const float e = __expf((lg[g] - m) * 0.25f);
                    sm += e;
                    go += e * vgr[g];
                }
                go /= sm;
                const int row = mt*16 + rg*4 + r;
                const int col = h*16 + cl;
                *(unsigned short*)(lds + 49152 + ((row*256 + col*2) ^ ((row & 7) << 4))) = f2bf(go);
            }
    }
    __syncthreads();  // barrier 5

    // ---------- Phase E: Y = O@Wout + G@(0.1*Woutg) + (bout + 0.1*boutg) ----------
    {
        const unsigned short* B2t = (const unsigned short*)(ws + WS_B2T);
        const float* bias2 = (const float*)(ws + WS_BIAS2);
        const int mt = wave >> 1, nh = wave & 1;
        f32x4 y[4];
        #pragma unroll
        for (int i = 0; i < 4; ++i) {
            const float bv = bias2[nh*64 + i*16 + cl];
            f32x4 t = {bv, bv, bv, bv};
            y[i] = t;
        }
        #pragma unroll
        for (int ks = 0; ks < 4; ++ks) {
            const int row = mt*16 + cl;
            const int co  = ks*32 + rg*8;
            const bf16x8 oa = *(const bf16x8*)(lds + 32768 + ((row*256 + co*2) ^ ((row & 7) << 4)));
            const bf16x8 ga = *(const bf16x8*)(lds + 49152 + ((row*256 + co*2) ^ ((row & 7) << 4)));
            #pragma unroll
            for (int i = 0; i < 4; ++i) {
                const int n = nh*64 + i*16 + cl;
                const bf16x8 wb = *(const bf16x8*)(B2t + n*128 + co);
                const bf16x8 wg = *(const bf16x8*)(B2t + (128 + n)*128 + co);
                y[i] = __builtin_amdgcn_mfma_f32_16x16x32_bf16(oa, wb, y[i], 0, 0, 0);
                y[i] = __builtin_amdgcn_mfma_f32_16x16x32_bf16(ga, wg, y[i], 0, 0, 0);
            }
        }
        #pragma unroll
        for (int i = 0; i < 4; ++i)
            #pragma unroll
            for (int r = 0; r < 4; ++r) {
                const int t = mt*16 + rg*4 + r;
                const int grow = base_row + (t >> 4)*1024 + ((t >> 2) & 3)*32 + (t & 3);
                out[grow*128 + nh*64 + i*16 + cl] = y[i][r];
            }
    }
}

extern "C" void kernel_launch(void* const* d_in, const int* in_sizes, int n_in,
                              void* d_out, int out_size, void* d_ws, size_t ws_size,
                              hipStream_t stream) {
    (void)in_sizes; (void)n_in; (void)out_size; (void)ws_size;
    const float* feat  = (const float*)d_in[0];
    const float* Wqkv  = (const float*)d_in[1];
    const float* bqkv  = (const float*)d_in[2];
    const float* Wout  = (const float*)d_in[3];
    const float* bout  = (const float*)d_in[4];
    const float* Wqg   = (const float*)d_in[5];
    const float* bqg   = (const float*)d_in[6];
    const float* Wkvg  = (const float*)d_in[7];
    const float* bkvg  = (const float*)d_in[8];
    const float* Woutg = (const float*)d_in[9];
    const float* boutg = (const float*)d_in[10];
    const float* gtok  = (const float*)d_in[11];
    unsigned char* ws  = (unsigned char*)d_ws;

    wattn_prep<<<dim3(13), dim3(256), 0, stream>>>(
        Wqkv, bqkv, Wout, bout, Wqg, bqg, Wkvg, bkvg, Woutg, boutg, gtok, ws);
    wattn_main<<<dim3(2048), dim3(512), 0, stream>>>(feat, ws, (float*)d_out);
}

// Round 2
// 259.980 us; speedup vs baseline: 1.5224x; 1.5224x over previous
//
#include <hip/hip_runtime.h>
#include <hip/hip_bf16.h>

typedef __bf16 bf16x8 __attribute__((ext_vector_type(8)));
typedef __bf16 bf16x4 __attribute__((ext_vector_type(4)));
typedef float  f32x4  __attribute__((ext_vector_type(4)));

// ---- workspace layout (bytes) ----
#define WS_B1T   0         // [512][128] bf16: [Wqkv | Wqg]^T  (n-major)
#define WS_B2T   131072    // [256][128] bf16: [Wout | 0.1*Woutg]^T
#define WS_BIAS1 196608    // f32[512] = [bqkv | bqg]
#define WS_BIAS2 198656    // f32[128] = bout + 0.1*boutg
#define WS_KVG   199168    // f32 kgT[8h][16d][8g] ; vgT at +4096B

// ---------------- prep: weights -> bf16 transposed, global KV, biases ----------------
__global__ __launch_bounds__(256) void wattn_prep(
    const float* __restrict__ Wqkv, const float* __restrict__ bqkv,
    const float* __restrict__ Wout, const float* __restrict__ bout,
    const float* __restrict__ Wqg,  const float* __restrict__ bqg,
    const float* __restrict__ Wkvg, const float* __restrict__ bkvg,
    const float* __restrict__ Woutg,const float* __restrict__ boutg,
    const float* __restrict__ gtok, unsigned char* __restrict__ ws)
{
    const int blk = blockIdx.x, tid = threadIdx.x;
    __bf16* B1t = (__bf16*)(ws + WS_B1T);
    __bf16* B2t = (__bf16*)(ws + WS_B2T);
    float* bias1 = (float*)(ws + WS_BIAS1);
    float* bias2 = (float*)(ws + WS_BIAS2);
    float* kvg   = (float*)(ws + WS_KVG);

    if (blk == 0) {
        // global-token KV, stored transposed: kgT[h][d][g], vgT[h][d][g]
        for (int i = tid; i < 2048; i += 256) {
            const int g = i >> 8, j = i & 255;
            float acc = bkvg[j];
            for (int c = 0; c < 128; ++c) acc += gtok[g*128 + c] * Wkvg[c*256 + j];
            const int half = j >> 7, hh = (j >> 4) & 7, d = j & 15;
            kvg[half*1024 + hh*128 + d*8 + g] = acc;
        }
        for (int i = tid; i < 512; i += 256) bias1[i] = (i < 384) ? bqkv[i] : bqg[i - 384];
        for (int i = tid; i < 128; i += 256) bias2[i] = bout[i] + 0.1f * boutg[i];
    } else if (blk <= 8) {
        const int n0 = (blk - 1) * 64;
        for (int i = tid; i < 64 * 128; i += 256) {
            const int n = n0 + (i >> 7), k = i & 127;
            const float w = (n < 384) ? Wqkv[k*384 + n] : Wqg[k*128 + (n - 384)];
            B1t[n*128 + k] = (__bf16)w;
        }
    } else {  // blk 9..12
        const int n0 = (blk - 9) * 64;
        for (int i = tid; i < 64 * 128; i += 256) {
            const int n = n0 + (i >> 7), k = i & 127;
            const float w = (n < 128) ? Wout[k*128 + n] : 0.1f * Woutg[k*128 + (n - 128)];
            B2t[n*128 + k] = (__bf16)w;
        }
    }
}

// ---------------- fused per-window kernel ----------------
// One wave per head (8 waves). LDS map (64 KiB):
//   [0,16K)    Xb features [64t][128c] swz((t&7)<<4)      -> O after barrier2
//   [16K,32K)  Q  per-wave 2K slots [64t][16d] swz((t&4)<<2)
//                -> P rows q32..63 -> qgT [16d][64t] swz((d&7)<<4)
//   [32K,48K)  K  per-wave 2K slots (same layout as Q)
//                -> P rows q0..31 -> G [64t][128c] swz((t&7)<<4)
//   [48K,64K)  Vt per-wave 2K slots [16d][64t] swz((d&7)<<4)
__global__ __launch_bounds__(512, 4) void wattn_main(
    const float* __restrict__ feat,
    const unsigned char* __restrict__ ws,
    float* __restrict__ out)
{
    __shared__ __align__(16) unsigned char lds[65536];
    const int tid  = threadIdx.x;
    const int h    = tid >> 6;    // wave = head
    const int lane = tid & 63;
    const int rg   = lane >> 4;
    const int cl   = lane & 15;

    const int blk = blockIdx.x;
    const int b   = blk >> 9;
    const int rem = blk & 511;
    const int base_row = b*32768 + (rem >> 6)*4096 + ((rem >> 3) & 7)*128 + (rem & 7)*4;

    const uint4 z4i = {0u, 0u, 0u, 0u};
    const bf16x8 zfrag = __builtin_bit_cast(bf16x8, z4i);
    const f32x4 z4 = {0.f, 0.f, 0.f, 0.f};

    unsigned char* Qs = lds + 16384 + h*2048;
    unsigned char* Ks = lds + 32768 + h*2048;
    unsigned char* Vs = lds + 49152 + h*2048;

    // ---------- Phase A: stage window features as bf16 (swizzled) ----------
    {
        const int row = tid >> 3, j = tid & 7;
        const int grow = base_row + (row >> 4)*1024 + ((row >> 2) & 3)*32 + (row & 3);
        const float* src = feat + grow*128;
        #pragma unroll
        for (int hh = 0; hh < 2; ++hh) {
            const int col = hh*64 + j*8;
            float4 a = *(const float4*)(src + col);
            float4 c = *(const float4*)(src + col + 4);
            bf16x8 v;
            v[0] = (__bf16)a.x; v[1] = (__bf16)a.y; v[2] = (__bf16)a.z; v[3] = (__bf16)a.w;
            v[4] = (__bf16)c.x; v[5] = (__bf16)c.y; v[6] = (__bf16)c.z; v[7] = (__bf16)c.w;
            *(bf16x8*)(lds + ((row*256 + col*2) ^ ((row & 7) << 4))) = v;
        }
    }
    __syncthreads();  // barrier 1

    // ---------- Phase B: [q k v qg] for own head = X @ B1t(+bias) ----------
    f32x4 acc[4][4];
    {
        const __bf16* B1t = (const __bf16*)(ws + WS_B1T);
        const float* bias1 = (const float*)(ws + WS_BIAS1);
        const int ntile[4] = {h, 8 + h, 16 + h, 24 + h};
        #pragma unroll
        for (int i = 0; i < 4; ++i) {
            const float bv = bias1[ntile[i]*16 + cl];
            f32x4 t = {bv, bv, bv, bv};
            #pragma unroll
            for (int mt = 0; mt < 4; ++mt) acc[mt][i] = t;
        }
        #pragma unroll
        for (int ks = 0; ks < 4; ++ks) {
            bf16x8 afr[4];
            #pragma unroll
            for (int mt = 0; mt < 4; ++mt) {
                const int row = mt*16 + cl, col = ks*32 + rg*8;
                afr[mt] = *(const bf16x8*)(lds + ((row*256 + col*2) ^ ((row & 7) << 4)));
            }
            #pragma unroll
            for (int i = 0; i < 4; ++i) {
                bf16x8 bfr = *(const bf16x8*)(B1t + ntile[i]*16*128 + cl*128 + ks*32 + rg*8);
                #pragma unroll
                for (int mt = 0; mt < 4; ++mt)
                    acc[mt][i] = __builtin_amdgcn_mfma_f32_16x16x32_bf16(afr[mt], bfr, acc[mt][i], 0, 0, 0);
            }
        }
    }
    // scatter: Q,K token-major scalar b16; V transposed packed b64
    #pragma unroll
    for (int mt = 0; mt < 4; ++mt) {
        #pragma unroll
        for (int r = 0; r < 4; ++r) {
            const int t = mt*16 + rg*4 + r;
            const int off = (t*32 + cl*2) ^ ((t & 4) << 2);
            *(__bf16*)(Qs + off) = (__bf16)acc[mt][0][r];
            *(__bf16*)(Ks + off) = (__bf16)acc[mt][1][r];
        }
        bf16x4 pv;
        #pragma unroll
        for (int r = 0; r < 4; ++r) pv[r] = (__bf16)acc[mt][2][r];
        const int t0 = mt*16 + rg*4;
        *(bf16x4*)(Vs + ((cl*128 + t0*2) ^ ((cl & 7) << 4))) = pv;
    }
    __syncthreads();  // barrier 2 (Xb dead -> O region free)

    // ---------- Phase C: local attention (own head, wave-private) ----------
    f32x4 o[4] = {z4, z4, z4, z4};
    float rinv[4];
    bf16x8 kf[4];
    #pragma unroll
    for (int kt = 0; kt < 4; ++kt) {
        if (rg < 2) {
            const int row = kt*16 + cl;
            kf[kt] = *(const bf16x8*)(Ks + ((row*32 + rg*16) ^ ((cl & 4) << 2)));
        } else kf[kt] = zfrag;
    }
    #pragma unroll
    for (int half = 0; half < 2; ++half) {
        const int q0t = half*2;
        bf16x8 qf[2];
        #pragma unroll
        for (int i = 0; i < 2; ++i) {
            if (rg < 2) {
                const int row = (q0t + i)*16 + cl;
                qf[i] = *(const bf16x8*)(Qs + ((row*32 + rg*16) ^ ((cl & 4) << 2)));
            } else qf[i] = zfrag;
        }
        f32x4 s[4][2];
        #pragma unroll
        for (int kt = 0; kt < 4; ++kt)
            #pragma unroll
            for (int i = 0; i < 2; ++i)
                s[kt][i] = __builtin_amdgcn_mfma_f32_16x16x32_bf16(kf[kt], qf[i], z4, 0, 0, 0);
        // softmax over k (16 lane-local + cross-rg shfl)
        #pragma unroll
        for (int i = 0; i < 2; ++i) {
            float m = -1e30f;
            #pragma unroll
            for (int kt = 0; kt < 4; ++kt)
                m = fmaxf(m, fmaxf(fmaxf(s[kt][i][0], s[kt][i][1]), fmaxf(s[kt][i][2], s[kt][i][3])));
            m = fmaxf(m, __shfl_xor(m, 16));
            m = fmaxf(m, __shfl_xor(m, 32));
            float sm = 0.f;
            #pragma unroll
            for (int kt = 0; kt < 4; ++kt)
                #pragma unroll
                for (int r = 0; r < 4; ++r) {
                    const float e = __expf((s[kt][i][r] - m) * 0.25f);
                    s[kt][i][r] = e;
                    sm += e;
                }
            sm += __shfl_xor(sm, 16);
            sm += __shfl_xor(sm, 32);
            rinv[q0t + i] = 1.0f / sm;
        }
        // P (unnormalized, packed b64) + PV per 32-key slab
        // half 0 (q 0..31) -> Ks rows; half 1 (q 32..63) -> Qs rows
        unsigned char* Pslot = half ? Qs : Ks;
        #pragma unroll
        for (int sl = 0; sl < 2; ++sl) {
            #pragma unroll
            for (int i = 0; i < 2; ++i) {
                const int q = (q0t + i)*16 + cl;
                unsigned char* Pb = Pslot + (q & 31)*64;
                #pragma unroll
                for (int kk = 0; kk < 2; ++kk) {
                    const int kt = sl*2 + kk;
                    bf16x4 pp;
                    #pragma unroll
                    for (int r = 0; r < 4; ++r) pp[r] = (__bf16)s[kt][i][r];
                    *(bf16x4*)(Pb + ((kk*32 + rg*8) ^ ((q & 3) << 4))) = pp;
                }
            }
            const bf16x8 vf = *(const bf16x8*)(Vs + ((cl*128 + sl*64 + rg*16) ^ ((cl & 7) << 4)));
            #pragma unroll
            for (int i = 0; i < 2; ++i) {
                const int q = (q0t + i)*16 + cl;
                const bf16x8 pf = *(const bf16x8*)(Pslot + (q & 31)*64 + ((rg*16) ^ ((q & 3) << 4)));
                o[q0t + i] = __builtin_amdgcn_mfma_f32_16x16x32_bf16(vf, pf, o[q0t + i], 0, 0, 0);
            }
        }
    }
    // O write (Xb region), fold 1/sum; O[t][c] rows 256B swz((t&7)<<4)
    #pragma unroll
    for (int qt = 0; qt < 4; ++qt) {
        const int t = qt*16 + cl;
        bf16x4 ov;
        #pragma unroll
        for (int r = 0; r < 4; ++r) ov[r] = (__bf16)(o[qt][r] * rinv[qt]);
        *(bf16x4*)(lds + ((t*256 + h*32 + rg*8) ^ ((t & 7) << 4)));
        *(bf16x4*)(lds + ((t*256 + h*32 + rg*8) ^ ((t & 7) << 4))) = ov;
    }
    // qgT write into own Q slot (P dead): [16d][64t] swz((d&7)<<4)
    #pragma unroll
    for (int mt = 0; mt < 4; ++mt) {
        bf16x4 pq;
        #pragma unroll
        for (int r = 0; r < 4; ++r) pq[r] = (__bf16)acc[mt][3][r];
        const int t0 = mt*16 + rg*4;
        *(bf16x4*)(Qs + ((cl*128 + t0*2) ^ ((cl & 7) << 4))) = pq;
    }

    // ---------- Phase D: global-token cross attention (lane = token) ----------
    float got[16];
    {
        float qgv[16];
        #pragma unroll
        for (int d = 0; d < 16; ++d)
            qgv[d] = (float)*(const __bf16*)(Qs + ((d*128 + lane*2) ^ ((d & 7) << 4)));
        const float* kgT = (const float*)(ws + WS_KVG) + h*128;
        const float* vgT = kgT + 1024;
        float lg[8] = {0.f,0.f,0.f,0.f,0.f,0.f,0.f,0.f};
        #pragma unroll
        for (int d = 0; d < 16; ++d) {
            const float4 k0 = *(const float4*)(kgT + d*8);
            const float4 k1 = *(const float4*)(kgT + d*8 + 4);
            const float qv = qgv[d];
            lg[0] += qv*k0.x; lg[1] += qv*k0.y; lg[2] += qv*k0.z; lg[3] += qv*k0.w;
            lg[4] += qv*k1.x; lg[5] += qv*k1.y; lg[6] += qv*k1.z; lg[7] += qv*k1.w;
        }
        float m = fmaxf(fmaxf(fmaxf(lg[0], lg[1]), fmaxf(lg[2], lg[3])),
                        fmaxf(fmaxf(lg[4], lg[5]), fmaxf(lg[6], lg[7])));
        float sm = 0.f;
        float p[8];
        #pragma unroll
        for (int g = 0; g < 8; ++g) { p[g] = __expf((lg[g] - m) * 0.25f); sm += p[g]; }
        const float rs = 1.0f / sm;
        #pragma unroll
        for (int g = 0; g < 8; ++g) p[g] *= rs;
        #pragma unroll
        for (int d = 0; d < 16; ++d) {
            const float4 v0 = *(const float4*)(vgT + d*8);
            const float4 v1 = *(const float4*)(vgT + d*8 + 4);
            got[d] = p[0]*v0.x + p[1]*v0.y + p[2]*v0.z + p[3]*v0.w
                   + p[4]*v1.x + p[5]*v1.y + p[6]*v1.z + p[7]*v1.w;
        }
    }
    __syncthreads();  // barrier 3: all waves done with K-block (P) -> G region free

    {   // G[t][c] bf16 over K block, rows 256B swz((t&7)<<4); lane = t, cols 16h..
        bf16x8 g0, g1;
        #pragma unroll
        for (int j = 0; j < 8; ++j) { g0[j] = (__bf16)got[j]; g1[j] = (__bf16)got[8 + j]; }
        *(bf16x8*)(lds + 32768 + ((lane*256 + h*32)      ^ ((lane & 7) << 4))) = g0;
        *(bf16x8*)(lds + 32768 + ((lane*256 + h*32 + 16) ^ ((lane & 7) << 4))) = g1;
    }
    __syncthreads();  // barrier 4

    // ---------- Phase E: Y^T = W2t . [O|G]^T  (wave owns n-tile h) ----------
    {
        const __bf16* B2t = (const __bf16*)(ws + WS_B2T);
        const float* bias2 = (const float*)(ws + WS_BIAS2);
        f32x4 y[4];
        const float4 bv = *(const float4*)(bias2 + h*16 + rg*4);
        #pragma unroll
        for (int tt = 0; tt < 4; ++tt) { f32x4 t = {bv.x, bv.y, bv.z, bv.w}; y[tt] = t; }
        #pragma unroll
        for (int ks = 0; ks < 4; ++ks) {
            const bf16x8 aW = *(const bf16x8*)(B2t + (h*16 + cl)*128 + ks*32 + rg*8);
            const bf16x8 aG = *(const bf16x8*)(B2t + (128 + h*16 + cl)*128 + ks*32 + rg*8);
            #pragma unroll
            for (int tt = 0; tt < 4; ++tt) {
                const int t = tt*16 + cl;
                const int off = (t*256 + ks*64 + rg*16) ^ ((t & 7) << 4);
                const bf16x8 bO = *(const bf16x8*)(lds + off);
                const bf16x8 bG = *(const bf16x8*)(lds + 32768 + off);
                y[tt] = __builtin_amdgcn_mfma_f32_16x16x32_bf16(aW, bO, y[tt], 0, 0, 0);
                y[tt] = __builtin_amdgcn_mfma_f32_16x16x32_bf16(aG, bG, y[tt], 0, 0, 0);
            }
        }
        #pragma unroll
        for (int tt = 0; tt < 4; ++tt) {
            const int grow = base_row + tt*1024 + (cl >> 2)*32 + (cl & 3);
            *(f32x4*)(out + grow*128 + h*16 + rg*4) = y[tt];
        }
    }
}

extern "C" void kernel_launch(void* const* d_in, const int* in_sizes, int n_in,
                              void* d_out, int out_size, void* d_ws, size_t ws_size,
                              hipStream_t stream) {
    (void)in_sizes; (void)n_in; (void)out_size; (void)ws_size;
    const float* feat  = (const float*)d_in[0];
    const float* Wqkv  = (const float*)d_in[1];
    const float* bqkv  = (const float*)d_in[2];
    const float* Wout  = (const float*)d_in[3];
    const float* bout  = (const float*)d_in[4];
    const float* Wqg   = (const float*)d_in[5];
    const float* bqg   = (const float*)d_in[6];
    const float* Wkvg  = (const float*)d_in[7];
    const float* bkvg  = (const float*)d_in[8];
    const float* Woutg = (const float*)d_in[9];
    const float* boutg = (const float*)d_in[10];
    const float* gtok  = (const float*)d_in[11];
    unsigned char* ws  = (unsigned char*)d_ws;

    wattn_prep<<<dim3(13), dim3(256), 0, stream>>>(
        Wqkv, bqkv, Wout, bout, Wqg, bqg, Wkvg, bkvg, Woutg, boutg, gtok, ws);
    wattn_main<<<dim3(2048), dim3(512), 0, stream>>>(feat, ws, (float*)d_out);
}

// Round 3
// 233.823 us; speedup vs baseline: 1.6927x; 1.1119x over previous
//
#include <hip/hip_runtime.h>
#include <hip/hip_bf16.h>

typedef __bf16 bf16x8 __attribute__((ext_vector_type(8)));
typedef __bf16 bf16x4 __attribute__((ext_vector_type(4)));
typedef float  f32x4  __attribute__((ext_vector_type(4)));

// ---- workspace layout (bytes) ----
#define WS_B1T   0         // [512][128] bf16: [Wqkv | Wqg]^T  (n-major)
#define WS_B2T   131072    // [256][128] bf16: [Wout | 0.1*Woutg]^T
#define WS_BIAS1 196608    // f32[512] = [bqkv | bqg]
#define WS_BIAS2 198656    // f32[128] = bout + 0.1*boutg
#define WS_KVG   199168    // f32 kgT[8h][16d][8g] ; vgT at +4096B

// ---------------- prep: fully parallel (57 blocks x 256 threads) ----------------
// blocks 0..31  : B1T transpose (coalesced reads, n-fastest)
// blocks 32..47 : B2T transpose
// blocks 48..55 : global-token KV (one g per block, one j per thread)
// block  56     : biases
__global__ __launch_bounds__(256) void wattn_prep(
    const float* __restrict__ Wqkv, const float* __restrict__ bqkv,
    const float* __restrict__ Wout, const float* __restrict__ bout,
    const float* __restrict__ Wqg,  const float* __restrict__ bqg,
    const float* __restrict__ Wkvg, const float* __restrict__ bkvg,
    const float* __restrict__ Woutg,const float* __restrict__ boutg,
    const float* __restrict__ gtok, unsigned char* __restrict__ ws)
{
    const int blk = blockIdx.x, tid = threadIdx.x;
    __bf16* B1t = (__bf16*)(ws + WS_B1T);
    __bf16* B2t = (__bf16*)(ws + WS_B2T);
    float* bias1 = (float*)(ws + WS_BIAS1);
    float* bias2 = (float*)(ws + WS_BIAS2);
    float* kvg   = (float*)(ws + WS_KVG);

    if (blk < 32) {
        #pragma unroll
        for (int j = 0; j < 8; ++j) {
            const int i = blk*2048 + j*256 + tid;
            const int k = i >> 9, n = i & 511;
            const float w = (n < 384) ? Wqkv[k*384 + n] : Wqg[k*128 + (n - 384)];
            B1t[n*128 + k] = (__bf16)w;
        }
    } else if (blk < 48) {
        #pragma unroll
        for (int j = 0; j < 8; ++j) {
            const int i = (blk - 32)*2048 + j*256 + tid;
            const int k = i >> 8, n = i & 255;
            const float w = (n < 128) ? Wout[k*128 + n] : 0.1f * Woutg[k*128 + (n - 128)];
            B2t[n*128 + k] = (__bf16)w;
        }
    } else if (blk < 56) {
        const int g = blk - 48;
        const int j = tid;   // 0..255
        float acc = bkvg[j];
        #pragma unroll 8
        for (int c = 0; c < 128; ++c) acc += gtok[g*128 + c] * Wkvg[c*256 + j];
        kvg[(j >> 7)*1024 + ((j >> 4) & 7)*128 + (j & 15)*8 + g] = acc;
    } else {
        for (int i = tid; i < 512; i += 256) bias1[i] = (i < 384) ? bqkv[i] : bqg[i - 384];
        for (int i = tid; i < 128; i += 256) bias2[i] = bout[i] + 0.1f * boutg[i];
    }
}

// ---------------- fused per-window kernel ----------------
// One wave per head (8 waves). LDS map (64 KiB):
//   [0,16K)    Xb features [64t][128c] swz((t&7)<<4)      -> O after barrier2
//   [16K,32K)  Q  per-wave 2K slots [64t][16d] swz((t&4)<<2)
//                -> P rows q32..63 -> qgT [16d][64t] swz((d&7)<<4)
//   [32K,48K)  K  per-wave 2K slots (same layout as Q)
//                -> P rows q0..31 -> G [64t][128c] swz((t&7)<<4)
//   [48K,64K)  Vt per-wave 2K slots [16d][64t] swz((d&7)<<4)
__global__ __launch_bounds__(512, 4) void wattn_main(
    const float* __restrict__ feat,
    const unsigned char* __restrict__ ws,
    float* __restrict__ out)
{
    __shared__ __align__(16) unsigned char lds[65536];
    const int tid  = threadIdx.x;
    const int h    = tid >> 6;    // wave = head
    const int lane = tid & 63;
    const int rg   = lane >> 4;
    const int cl   = lane & 15;

    const int blk = blockIdx.x;
    const int b   = blk >> 9;
    const int rem = blk & 511;
    const int base_row = b*32768 + (rem >> 6)*4096 + ((rem >> 3) & 7)*128 + (rem & 7)*4;

    const uint4 z4i = {0u, 0u, 0u, 0u};
    const bf16x8 zfrag = __builtin_bit_cast(bf16x8, z4i);
    const f32x4 z4 = {0.f, 0.f, 0.f, 0.f};

    unsigned char* Qs = lds + 16384 + h*2048;
    unsigned char* Ks = lds + 32768 + h*2048;
    unsigned char* Vs = lds + 49152 + h*2048;

    // ---------- Phase A: stage window features as bf16 (swizzled) ----------
    {
        const int row = tid >> 3, j = tid & 7;
        const int grow = base_row + (row >> 4)*1024 + ((row >> 2) & 3)*32 + (row & 3);
        const float* src = feat + grow*128;
        #pragma unroll
        for (int hh = 0; hh < 2; ++hh) {
            const int col = hh*64 + j*8;
            float4 a = *(const float4*)(src + col);
            float4 c = *(const float4*)(src + col + 4);
            bf16x8 v;
            v[0] = (__bf16)a.x; v[1] = (__bf16)a.y; v[2] = (__bf16)a.z; v[3] = (__bf16)a.w;
            v[4] = (__bf16)c.x; v[5] = (__bf16)c.y; v[6] = (__bf16)c.z; v[7] = (__bf16)c.w;
            *(bf16x8*)(lds + ((row*256 + col*2) ^ ((row & 7) << 4))) = v;
        }
    }
    __syncthreads();  // barrier 1

    // ---------- Phase B: [q k v qg] for own head = X @ B1t(+bias) ----------
    f32x4 acc[4][4];
    {
        const __bf16* B1t = (const __bf16*)(ws + WS_B1T);
        const float* bias1 = (const float*)(ws + WS_BIAS1);
        const int ntile[4] = {h, 8 + h, 16 + h, 24 + h};
        #pragma unroll
        for (int i = 0; i < 4; ++i) {
            const float bv = bias1[ntile[i]*16 + cl];
            f32x4 t = {bv, bv, bv, bv};
            #pragma unroll
            for (int mt = 0; mt < 4; ++mt) acc[mt][i] = t;
        }
        #pragma unroll
        for (int ks = 0; ks < 4; ++ks) {
            bf16x8 afr[4];
            #pragma unroll
            for (int mt = 0; mt < 4; ++mt) {
                const int row = mt*16 + cl, col = ks*32 + rg*8;
                afr[mt] = *(const bf16x8*)(lds + ((row*256 + col*2) ^ ((row & 7) << 4)));
            }
            #pragma unroll
            for (int i = 0; i < 4; ++i) {
                bf16x8 bfr = *(const bf16x8*)(B1t + ntile[i]*16*128 + cl*128 + ks*32 + rg*8);
                #pragma unroll
                for (int mt = 0; mt < 4; ++mt)
                    acc[mt][i] = __builtin_amdgcn_mfma_f32_16x16x32_bf16(afr[mt], bfr, acc[mt][i], 0, 0, 0);
            }
        }
    }
    // scatter: Q,K token-major scalar b16; V transposed packed b64
    #pragma unroll
    for (int mt = 0; mt < 4; ++mt) {
        #pragma unroll
        for (int r = 0; r < 4; ++r) {
            const int t = mt*16 + rg*4 + r;
            const int off = (t*32 + cl*2) ^ ((t & 4) << 2);
            *(__bf16*)(Qs + off) = (__bf16)acc[mt][0][r];
            *(__bf16*)(Ks + off) = (__bf16)acc[mt][1][r];
        }
        bf16x4 pv;
        #pragma unroll
        for (int r = 0; r < 4; ++r) pv[r] = (__bf16)acc[mt][2][r];
        const int t0 = mt*16 + rg*4;
        *(bf16x4*)(Vs + ((cl*128 + t0*2) ^ ((cl & 7) << 4))) = pv;
    }
    __syncthreads();  // barrier 2 (Xb dead -> O region free)

    // ---------- Phase C: local attention (own head, wave-private) ----------
    f32x4 o[4] = {z4, z4, z4, z4};
    float rinv[4];
    bf16x8 kf[4];
    #pragma unroll
    for (int kt = 0; kt < 4; ++kt) {
        if (rg < 2) {
            const int row = kt*16 + cl;
            kf[kt] = *(const bf16x8*)(Ks + ((row*32 + rg*16) ^ ((cl & 4) << 2)));
        } else kf[kt] = zfrag;
    }
    #pragma unroll
    for (int half = 0; half < 2; ++half) {
        const int q0t = half*2;
        bf16x8 qf[2];
        #pragma unroll
        for (int i = 0; i < 2; ++i) {
            if (rg < 2) {
                const int row = (q0t + i)*16 + cl;
                qf[i] = *(const bf16x8*)(Qs + ((row*32 + rg*16) ^ ((cl & 4) << 2)));
            } else qf[i] = zfrag;
        }
        f32x4 s[4][2];
        #pragma unroll
        for (int kt = 0; kt < 4; ++kt)
            #pragma unroll
            for (int i = 0; i < 2; ++i)
                s[kt][i] = __builtin_amdgcn_mfma_f32_16x16x32_bf16(kf[kt], qf[i], z4, 0, 0, 0);
        // softmax over k (16 lane-local + cross-rg shfl)
        #pragma unroll
        for (int i = 0; i < 2; ++i) {
            float m = -1e30f;
            #pragma unroll
            for (int kt = 0; kt < 4; ++kt)
                m = fmaxf(m, fmaxf(fmaxf(s[kt][i][0], s[kt][i][1]), fmaxf(s[kt][i][2], s[kt][i][3])));
            m = fmaxf(m, __shfl_xor(m, 16));
            m = fmaxf(m, __shfl_xor(m, 32));
            float sm = 0.f;
            #pragma unroll
            for (int kt = 0; kt < 4; ++kt)
                #pragma unroll
                for (int r = 0; r < 4; ++r) {
                    const float e = __expf((s[kt][i][r] - m) * 0.25f);
                    s[kt][i][r] = e;
                    sm += e;
                }
            sm += __shfl_xor(sm, 16);
            sm += __shfl_xor(sm, 32);
            rinv[q0t + i] = 1.0f / sm;
        }
        // P (unnormalized, packed b64) + PV per 32-key slab
        // half 0 (q 0..31) -> Ks rows; half 1 (q 32..63) -> Qs rows
        unsigned char* Pslot = half ? Qs : Ks;
        #pragma unroll
        for (int sl = 0; sl < 2; ++sl) {
            #pragma unroll
            for (int i = 0; i < 2; ++i) {
                const int q = (q0t + i)*16 + cl;
                unsigned char* Pb = Pslot + (q & 31)*64;
                #pragma unroll
                for (int kk = 0; kk < 2; ++kk) {
                    const int kt = sl*2 + kk;
                    bf16x4 pp;
                    #pragma unroll
                    for (int r = 0; r < 4; ++r) pp[r] = (__bf16)s[kt][i][r];
                    *(bf16x4*)(Pb + ((kk*32 + rg*8) ^ ((q & 3) << 4))) = pp;
                }
            }
            const bf16x8 vf = *(const bf16x8*)(Vs + ((cl*128 + sl*64 + rg*16) ^ ((cl & 7) << 4)));
            #pragma unroll
            for (int i = 0; i < 2; ++i) {
                const int q = (q0t + i)*16 + cl;
                const bf16x8 pf = *(const bf16x8*)(Pslot + (q & 31)*64 + ((rg*16) ^ ((q & 3) << 4)));
                o[q0t + i] = __builtin_amdgcn_mfma_f32_16x16x32_bf16(vf, pf, o[q0t + i], 0, 0, 0);
            }
        }
    }
    // O write (Xb region), fold 1/sum; O[t][c] rows 256B swz((t&7)<<4)
    #pragma unroll
    for (int qt = 0; qt < 4; ++qt) {
        const int t = qt*16 + cl;
        bf16x4 ov;
        #pragma unroll
        for (int r = 0; r < 4; ++r) ov[r] = (__bf16)(o[qt][r] * rinv[qt]);
        *(bf16x4*)(lds + ((t*256 + h*32 + rg*8) ^ ((t & 7) << 4))) = ov;
    }
    // qgT write into own Q slot (P dead): [16d][64t] swz((d&7)<<4)
    #pragma unroll
    for (int mt = 0; mt < 4; ++mt) {
        bf16x4 pq;
        #pragma unroll
        for (int r = 0; r < 4; ++r) pq[r] = (__bf16)acc[mt][3][r];
        const int t0 = mt*16 + rg*4;
        *(bf16x4*)(Qs + ((cl*128 + t0*2) ^ ((cl & 7) << 4))) = pq;
    }

    // ---------- Phase D: global-token cross attention (lane = token) ----------
    float got[16];
    {
        float qgv[16];
        #pragma unroll
        for (int d = 0; d < 16; ++d)
            qgv[d] = (float)*(const __bf16*)(Qs + ((d*128 + lane*2) ^ ((d & 7) << 4)));
        const float* kgT = (const float*)(ws + WS_KVG) + h*128;
        const float* vgT = kgT + 1024;
        float lg[8] = {0.f,0.f,0.f,0.f,0.f,0.f,0.f,0.f};
        #pragma unroll
        for (int d = 0; d < 16; ++d) {
            const float4 k0 = *(const float4*)(kgT + d*8);
            const float4 k1 = *(const float4*)(kgT + d*8 + 4);
            const float qv = qgv[d];
            lg[0] += qv*k0.x; lg[1] += qv*k0.y; lg[2] += qv*k0.z; lg[3] += qv*k0.w;
            lg[4] += qv*k1.x; lg[5] += qv*k1.y; lg[6] += qv*k1.z; lg[7] += qv*k1.w;
        }
        float m = fmaxf(fmaxf(fmaxf(lg[0], lg[1]), fmaxf(lg[2], lg[3])),
                        fmaxf(fmaxf(lg[4], lg[5]), fmaxf(lg[6], lg[7])));
        float sm = 0.f;
        float p[8];
        #pragma unroll
        for (int g = 0; g < 8; ++g) { p[g] = __expf((lg[g] - m) * 0.25f); sm += p[g]; }
        const float rs = 1.0f / sm;
        #pragma unroll
        for (int g = 0; g < 8; ++g) p[g] *= rs;
        #pragma unroll
        for (int d = 0; d < 16; ++d) {
            const float4 v0 = *(const float4*)(vgT + d*8);
            const float4 v1 = *(const float4*)(vgT + d*8 + 4);
            got[d] = p[0]*v0.x + p[1]*v0.y + p[2]*v0.z + p[3]*v0.w
                   + p[4]*v1.x + p[5]*v1.y + p[6]*v1.z + p[7]*v1.w;
        }
    }
    __syncthreads();  // barrier 3: all waves done with K-block (P) -> G region free

    {   // G[t][c] bf16 over K block, rows 256B swz((t&7)<<4); lane = t, cols 16h..
        bf16x8 g0, g1;
        #pragma unroll
        for (int j = 0; j < 8; ++j) { g0[j] = (__bf16)got[j]; g1[j] = (__bf16)got[8 + j]; }
        *(bf16x8*)(lds + 32768 + ((lane*256 + h*32)      ^ ((lane & 7) << 4))) = g0;
        *(bf16x8*)(lds + 32768 + ((lane*256 + h*32 + 16) ^ ((lane & 7) << 4))) = g1;
    }
    __syncthreads();  // barrier 4

    // ---------- Phase E: Y^T = W2t . [O|G]^T  (wave owns n-tile h) ----------
    {
        const __bf16* B2t = (const __bf16*)(ws + WS_B2T);
        const float* bias2 = (const float*)(ws + WS_BIAS2);
        f32x4 y[4];
        const float4 bv = *(const float4*)(bias2 + h*16 + rg*4);
        #pragma unroll
        for (int tt = 0; tt < 4; ++tt) { f32x4 t = {bv.x, bv.y, bv.z, bv.w}; y[tt] = t; }
        #pragma unroll
        for (int ks = 0; ks < 4; ++ks) {
            const bf16x8 aW = *(const bf16x8*)(B2t + (h*16 + cl)*128 + ks*32 + rg*8);
            const bf16x8 aG = *(const bf16x8*)(B2t + (128 + h*16 + cl)*128 + ks*32 + rg*8);
            #pragma unroll
            for (int tt = 0; tt < 4; ++tt) {
                const int t = tt*16 + cl;
                const int off = (t*256 + ks*64 + rg*16) ^ ((t & 7) << 4);
                const bf16x8 bO = *(const bf16x8*)(lds + off);
                const bf16x8 bG = *(const bf16x8*)(lds + 32768 + off);
                y[tt] = __builtin_amdgcn_mfma_f32_16x16x32_bf16(aW, bO, y[tt], 0, 0, 0);
                y[tt] = __builtin_amdgcn_mfma_f32_16x16x32_bf16(aG, bG, y[tt], 0, 0, 0);
            }
        }
        #pragma unroll
        for (int tt = 0; tt < 4; ++tt) {
            const int grow = base_row + tt*1024 + (cl >> 2)*32 + (cl & 3);
            *(f32x4*)(out + grow*128 + h*16 + rg*4) = y[tt];
        }
    }
}

extern "C" void kernel_launch(void* const* d_in, const int* in_sizes, int n_in,
                              void* d_out, int out_size, void* d_ws, size_t ws_size,
                              hipStream_t stream) {
    (void)in_sizes; (void)n_in; (void)out_size; (void)ws_size;
    const float* feat  = (const float*)d_in[0];
    const float* Wqkv  = (const float*)d_in[1];
    const float* bqkv  = (const float*)d_in[2];
    const float* Wout  = (const float*)d_in[3];
    const float* bout  = (const float*)d_in[4];
    const float* Wqg   = (const float*)d_in[5];
    const float* bqg   = (const float*)d_in[6];
    const float* Wkvg  = (const float*)d_in[7];
    const float* bkvg  = (const float*)d_in[8];
    const float* Woutg = (const float*)d_in[9];
    const float* boutg = (const float*)d_in[10];
    const float* gtok  = (const float*)d_in[11];
    unsigned char* ws  = (unsigned char*)d_ws;

    wattn_prep<<<dim3(57), dim3(256), 0, stream>>>(
        Wqkv, bqkv, Wout, bout, Wqg, bqg, Wkvg, bkvg, Woutg, boutg, gtok, ws);
    wattn_main<<<dim3(2048), dim3(512), 0, stream>>>(feat, ws, (float*)d_out);
}